// Round 10
// baseline (156.579 us; speedup 1.0000x reference)
//
#include <hip/hip_runtime.h>
#include <hip/hip_bf16.h>

#define B_BATCH 512
#define NPB     500
#define DIM     128
#define VOCAB   50000
#define MAXD    40
#define NPREP   512
#define NCONV   768
#define NGEMM   ((VOCAB + 63) / 64)   // 782
#define EMB_OCT (VOCAB * 16)          // 800000 octets (50000 = 16*3125, exact)

typedef short bf16x8 __attribute__((ext_vector_type(8)));
typedef float f32x4  __attribute__((ext_vector_type(4)));

__device__ __forceinline__ unsigned short f2bf(float x) {
    unsigned u = __float_as_uint(x);
    return (unsigned short)((u + 0x7fffu + ((u >> 16) & 1u)) >> 16);   // RTNE
}

// ---------- fused prep (blocks 0..511) + one-time bf16 frag-order convert ----
// prep: per-tree DFS (tin/end), round-7 algorithm. conv (blocks 512..1279):
// emb -> embB (bf16, A-frag octet order: per 16-row group, octet o*16+mc) and
// Wc -> WcB (bf16, B-frag order). This hoists ALL f2bf + swizzle out of the
// gemm grid (r9 re-did the Wc swizzle 782x = 12.8M VALU ops + 1.5M bank cnfl).
__global__ __launch_bounds__(256) void conv_prep(const int* __restrict__ tokens,
                                                 const int* __restrict__ parent,
                                                 const int* __restrict__ depth,
                                                 const float* __restrict__ emb,
                                                 const float* __restrict__ Wc,
                                                 int* __restrict__ tokD,
                                                 unsigned short* __restrict__ endD,
                                                 unsigned short* __restrict__ embB,
                                                 unsigned short* __restrict__ WcB) {
    const int tid = threadIdx.x;

    if (blockIdx.x >= NPREP) {
        // ================= CONV branch =================
        const int ct = (blockIdx.x - NPREP) * 256 + tid;
        // emb: octet i -> row r=(i>>8)*16|(i&15), k-octet o=(i>>4)&15
        for (int i = ct; i < EMB_OCT; i += NCONV * 256) {
            int r = ((i >> 8) << 4) | (i & 15);
            int o = (i >> 4) & 15;
            const float* src = &emb[(long long)r * DIM + o * 8];
            float4 v0 = *(const float4*)src;
            float4 v1 = *(const float4*)(src + 4);
            unsigned short w[8] = {f2bf(v0.x), f2bf(v0.y), f2bf(v0.z), f2bf(v0.w),
                                   f2bf(v1.x), f2bf(v1.y), f2bf(v1.z), f2bf(v1.w)};
            *(bf16x8*)&embB[(long long)i * 8] = *(bf16x8*)w;
        }
        // Wc: octet ob = (kc*8+nt)*64+ln ; k = kc*32+(ln>>4)*8+j ; n = nt*16+(ln&15)
        for (int i = ct; i < 2048; i += NCONV * 256) {
            int kc = i >> 9, nt = (i >> 6) & 7, ln = i & 63;
            int col   = (nt << 4) | (ln & 15);
            int kbase = kc * 32 + (ln >> 4) * 8;
            unsigned short w[8];
            #pragma unroll
            for (int j = 0; j < 8; ++j) w[j] = f2bf(Wc[(kbase + j) * DIM + col]);
            *(bf16x8*)&WcB[i * 8] = *(bf16x8*)w;
        }
        return;
    }

    // ================= PREP branch (r7 algorithm, unchanged) =================
    __shared__ unsigned short parL[NPB];
    __shared__ unsigned short depL[NPB];
    __shared__ int   tokL[NPB];
    __shared__ int   sizeL[NPB];
    __shared__ int   pack[NPB];
    __shared__ unsigned short sibp[NPB];
    __shared__ unsigned short tinL[NPB];
    __shared__ unsigned short bucket[NPB];
    __shared__ int hist[MAXD + 1], off[MAXD + 1], cur[MAXD + 1];
    __shared__ int tmpTok[NPB];
    __shared__ unsigned short tmpEnd[NPB];
    __shared__ int sdmax;

    const int b = blockIdx.x;
    const long long base = (long long)b * NPB;

    if (tid <= MAXD) hist[tid] = 0;
    __syncthreads();
    for (int n = tid; n < NPB; n += 256) {
        int d = depth[base + n];
        depL[n]  = (unsigned short)d;
        parL[n]  = (unsigned short)(n == 0 ? 0 : (int)(parent[base + n] - base));
        tokL[n]  = tokens[base + n];
        sizeL[n] = 1;
        if (n > 0) atomicAdd(&hist[d], 1);
    }
    __syncthreads();

    if (tid < 64) {
        int h = (tid >= 1 && tid <= MAXD) ? hist[tid] : 0;
        int x = h;
        #pragma unroll
        for (int o = 1; o < 64; o <<= 1) { int y = __shfl_up(x, o, 64); if (tid >= o) x += y; }
        if (tid >= 1 && tid <= MAXD) { off[tid] = x - h; cur[tid] = x - h; }
        int dm = (h > 0) ? tid : 0;
        #pragma unroll
        for (int o = 32; o; o >>= 1) dm = max(dm, __shfl_down(dm, o));
        if (tid == 0) sdmax = dm;
    }
    __syncthreads();

    for (int n = 1 + tid; n < NPB; n += 256)
        bucket[atomicAdd(&cur[depL[n]], 1)] = (unsigned short)n;
    __syncthreads();
    const int dmax = sdmax;

    for (int d = dmax; d >= 1; --d) {
        int c = hist[d], o = off[d];
        for (int i = tid; i < c; i += 256) {
            int n = bucket[o + i];
            atomicAdd(&sizeL[parL[n]], sizeL[n]);
        }
        __syncthreads();
    }

    for (int n = tid; n < NPB; n += 256) pack[n] = (int)parL[n] | (sizeL[n] << 16);
    __syncthreads();

    {
        int n0 = tid, n1 = tid + 256;
        int p0 = parL[n0];
        int p1 = (n1 < NPB) ? parL[n1] : -1;
        int a0 = 0, a1 = 0;
        for (int m = 1; m < NPB; ++m) {
            int pk = pack[m];
            int pm = pk & 0xffff, sm = pk >> 16;
            if (m < n0 && pm == p0) a0 += sm;
            if (m < n1 && pm == p1) a1 += sm;
        }
        if (n0 >= 1) sibp[n0] = (unsigned short)a0;
        if (n1 >= 1 && n1 < NPB) sibp[n1] = (unsigned short)a1;
        if (tid == 0) tinL[0] = 0;
    }
    __syncthreads();

    for (int d = 1; d <= dmax; ++d) {
        int c = hist[d], o = off[d];
        for (int i = tid; i < c; i += 256) {
            int n = bucket[o + i];
            tinL[n] = (unsigned short)((int)tinL[parL[n]] + 1 + (int)sibp[n]);
        }
        __syncthreads();
    }

    for (int n = tid; n < NPB; n += 256) {
        int t = tinL[n];
        tmpTok[t] = tokL[n];
        tmpEnd[t] = (unsigned short)(t + sizeL[n] - 1);
    }
    __syncthreads();
    for (int t = tid; t < NPB; t += 256) {
        tokD[base + t] = tmpTok[t];
        endD[base + t] = tmpEnd[t];
    }
}

// ---------------- pure-MFMA streaming GEMM: E = embB @ WcB + bc ----------------
// No LDS, no barriers, no conversions. A-frags and B-frags load directly from
// the pre-swizzled global arrays as contiguous bf16x8 (coalesced 1KB/wave);
// WcB (32 KB) is L2-resident and shared by all blocks. 64 rows/block.
__global__ __launch_bounds__(256) void gemm_k(const unsigned short* __restrict__ embB,
                                              const unsigned short* __restrict__ WcB,
                                              const float* __restrict__ bc,
                                              float* __restrict__ E) {
    const int tid = threadIdx.x;
    const int lane = tid & 63, w = tid >> 6;
    const int q = lane >> 4, mc = lane & 15;
    const long long tile = blockIdx.x;
    const int rowBase = (int)tile * 64;

    const bf16x8* Ao = (const bf16x8*)embB + (tile * 4 + w) * 256;  // 256 octets/group
    const bf16x8* Bo = (const bf16x8*)WcB;

    f32x4 acc[8];
    #pragma unroll
    for (int nt = 0; nt < 8; ++nt) acc[nt] = (f32x4){0.f, 0.f, 0.f, 0.f};

    #pragma unroll
    for (int kc = 0; kc < 4; ++kc) {
        bf16x8 a = Ao[(kc * 4 + q) * 16 + mc];
        #pragma unroll
        for (int nt = 0; nt < 8; ++nt) {
            bf16x8 bf = Bo[(kc * 8 + nt) * 64 + lane];
            acc[nt] = __builtin_amdgcn_mfma_f32_16x16x32_bf16(a, bf, acc[nt], 0, 0, 0);
        }
    }

    // C/D: row=(lane>>4)*4+reg, col=lane&15 per 16x16 tile
    #pragma unroll
    for (int nt = 0; nt < 8; ++nt) {
        float bcv = bc[nt * 16 + mc];
        #pragma unroll
        for (int r = 0; r < 4; ++r) {
            int grow = rowBase + w * 16 + q * 4 + r;
            if (grow < VOCAB)
                E[(long long)grow * DIM + nt * 16 + mc] = acc[nt][r] + bcv;
        }
    }
}

// ---------------- fused gather + prefix-scan + subtree-max (r9, unchanged) ----
__global__ __launch_bounds__(512, 4) void scan_k(const int* __restrict__ tokD,
                                                 const unsigned short* __restrict__ endD,
                                                 const float* __restrict__ E,
                                                 float* __restrict__ out) {
    const int b = blockIdx.x & 511, s = blockIdx.x >> 9, tid = threadIdx.x;
    const long long base = (long long)b * NPB;
    __shared__ float S[NPB * 32];             // 64000 B
    __shared__ int tokL[NPB];
    __shared__ unsigned short endL[NPB];
    __shared__ float partials[16 * 32];
    __shared__ float wmax[8 * 32];

    if (tid < NPB) {
        tokL[tid] = tokD[base + tid];
        endL[tid] = endD[base + tid];
    }
    __syncthreads();

    #pragma unroll
    for (int u = 0; u < 8; ++u) {
        int i = tid + u * 512;
        if (i < NPB * 8) {
            const float* g = &E[(long long)tokL[i >> 3] * DIM + s * 32 + (i & 7) * 4];
            __builtin_amdgcn_global_load_lds(
                (const __attribute__((address_space(1))) void*)g,
                (__attribute__((address_space(3))) void*)&S[i * 4], 16, 0, 0);
        }
    }
    __syncthreads();

    const int j = tid & 31, c = tid >> 5;
    float x[32];
    {
        float run = 0.f;
        #pragma unroll
        for (int k = 0; k < 32; ++k) {
            int t = c * 32 + k;
            float v = (t < NPB) ? S[t * 32 + j] : 0.f;
            run += v; x[k] = run;
        }
        partials[c * 32 + j] = run;
    }
    __syncthreads();
    float off = 0.f;
    for (int cc = 0; cc < c; ++cc) off += partials[cc * 32 + j];
    #pragma unroll
    for (int k = 0; k < 32; ++k) {
        int t = c * 32 + k;
        x[k] += off;
        if (t < NPB) S[t * 32 + j] = x[k];
    }
    __syncthreads();

    float m = -INFINITY;
    #pragma unroll
    for (int k = 0; k < 32; ++k) {
        int t = c * 32 + k;
        if (t < NPB) {
            float hi = S[(int)endL[t] * 32 + j];
            float lo = (k > 0) ? x[k - 1] : off;
            m = fmaxf(m, hi - lo);
        }
    }
    m = fmaxf(m, __shfl_down(m, 32));
    if ((tid & 63) < 32) wmax[(tid >> 6) * 32 + j] = m;
    __syncthreads();
    if (tid < 32) {
        float mm = wmax[tid];
        #pragma unroll
        for (int w = 1; w < 8; ++w) mm = fmaxf(mm, wmax[w * 32 + tid]);
        out[b * DIM + s * 32 + tid] = fmaxf(mm, 0.0f);
    }
}

extern "C" void kernel_launch(void* const* d_in, const int* in_sizes, int n_in,
                              void* d_out, int out_size, void* d_ws, size_t ws_size,
                              hipStream_t stream) {
    const int*   tokens = (const int*)d_in[0];
    const int*   parent = (const int*)d_in[1];
    const int*   depth  = (const int*)d_in[2];
    // d_in[3] = node2batch (unused: node2batch[n] == n / 500 by construction)
    const float* emb    = (const float*)d_in[4];
    const float* Wc     = (const float*)d_in[5];
    const float* bc     = (const float*)d_in[6];
    float*       out    = (float*)d_out;

    float*          E    = (float*)d_ws;                              // 25.6 MB
    unsigned short* embB = (unsigned short*)(E + (long long)VOCAB * DIM); // 12.8 MB
    unsigned short* WcB  = embB + (long long)NGEMM * 64 * DIM;        // 32 KB
    int*            tokD = (int*)(WcB + DIM * DIM);                   // 1 MB
    unsigned short* endD = (unsigned short*)(tokD + B_BATCH * NPB);   // 0.5 MB

    conv_prep<<<NPREP + NCONV, 256, 0, stream>>>(tokens, parent, depth, emb, Wc,
                                                 tokD, endD, embB, WcB);
    gemm_k<<<NGEMM, 256, 0, stream>>>(embB, WcB, bc, E);
    scan_k<<<B_BATCH * 4, 512, 0, stream>>>(tokD, endD, E, out);
}